// Round 7
// baseline (12453.120 us; speedup 1.0000x reference)
//
#include <hip/hip_runtime.h>
#include <hip/hip_bf16.h>

// ---------------------------------------------------------------------------
// LSTM: T=256, B=128, F=1024, H=1024.  gates = [x_t | h] @ [W_ih; W_hh] + bias
// Persistent kernel, 256 WGs. r=(wg>>3)&3 (32-row group), j=(wg&7)*8+(wg>>5)
// (16-col group). Wave = gate. bf16 MFMA 16x16x32. All 64 B-fragments
// register-resident (R4). Fence-free IF-coherent h publish (R5). Direct
// gather-poll (R6). Batched asm h-loads + gemm_x overlap (R7).
//
// R10 = hardened R9 (R9 died to an infra-shaped failure; theory untested).
// L2-BROADCAST via PER-XCD LEADER INVALIDATE: h-read is byte-bound on the
// coherent IF path (16 MiB/step @ ~2 TB/s ~ 8 us). One leader WG per
// physical XCD (numeric hwreg(20)=XCC_ID, masked; atomic rank election)
// executes the acquire fence (buffer_inv) once per step after its global
// poll, then raises a per-XCD flag (plain store -> dirty in LOCAL L2).
// Same-XCD WGs spin on the flag with local sc0 polls, then read pH with
// sc0 (L1-bypass, L2-cached): 1 MALL miss + 15/16 L2 hits per line
// (2 MiB/step MALL instead of 16 MiB).
// Hardening vs R9:
//  - numeric hwreg(20,0,32) & 7 (no named-hwreg assembler dependency)
//  - leader raises the flag UNCONDITIONALLY (leadership needs no self-l2m)
//  - probe validation: only WGs sharing the leader's physical L2 see its
//    unflushed dirty nonce -> cross-XCD-mapped WGs demote to sc1 (R7) path
//  - per-step flag wait has a one-shot timeout -> STICKY demotion (no
//    deadlock even if probe false-positived via eviction-writeback)
//  - all cnt indices bounded < 4096 ints (R8's suspected OOB fixed)
// Race-safety: leader inv happens post-poll => after all step-(t-1) pH
// reads drained chip-wide; dirty lines survive inv (R4 precedent); pX/x
// immutable so inv-refetches are value-safe.
// Workspace tiers: counters(16K) | pB(16M) | pH(512K) | pX(64M);
// tier D: pB packed into out rows [224,256).
// ---------------------------------------------------------------------------

typedef __attribute__((ext_vector_type(8))) short short8;   // 8 bf16 = 4 VGPRs
typedef __attribute__((ext_vector_type(4))) float floatx4;  // MFMA accumulator

#define HID_OFF 33554432L   // T*B*H
#define CT_OFF  33685504L   // T*B*H + B*H
#define WTAIL_F 29360128L   // 224*131072 : float offset of hid rows [224,256)

__device__ __forceinline__ unsigned short f2bf(float f) {
    __hip_bfloat16 hb = __float2bfloat16(f);
    return *reinterpret_cast<unsigned short*>(&hb);
}

// 8 contiguous fp32 -> 8 bf16 packed in a uint4
__device__ __forceinline__ uint4 pack8(const float* p) {
    float4 f0 = *reinterpret_cast<const float4*>(p);
    float4 f1 = *reinterpret_cast<const float4*>(p + 4);
    union { uint4 v; unsigned short u[8]; } t;
    t.u[0] = f2bf(f0.x); t.u[1] = f2bf(f0.y); t.u[2] = f2bf(f0.z); t.u[3] = f2bf(f0.w);
    t.u[4] = f2bf(f1.x); t.u[5] = f2bf(f1.y); t.u[6] = f2bf(f1.z); t.u[7] = f2bf(f1.w);
    return t.v;
}

// ---- pack weights into B-fragment order: frag=(nblk*64+kblk), lane, 8 bf16 ----
__global__ void pack_w_kernel(const float* __restrict__ wih,
                              const float* __restrict__ whh,
                              unsigned short* __restrict__ pB) {
    int g    = blockIdx.x * 256 + threadIdx.x;   // 1,048,576 threads
    int lane = g & 63;
    int frag = g >> 6;
    int kblk = frag & 63;
    int nblk = frag >> 6;
    int n = nblk * 16 + (lane & 15);
    int k = kblk * 32 + ((lane >> 4) << 3);
    const float* src = (k < 1024) ? (wih + (size_t)k * 4096 + n)
                                  : (whh + (size_t)(k - 1024) * 4096 + n);
    __attribute__((aligned(16))) unsigned short tmp[8];
#pragma unroll
    for (int jj = 0; jj < 8; ++jj) tmp[jj] = f2bf(src[(size_t)jj * 4096]);
    *reinterpret_cast<uint4*>(pB + (size_t)frag * 512 + lane * 8) =
        *reinterpret_cast<const uint4*>(tmp);
}

// ---- pack x into A-fragment order: frag=(t*256 + mblk*32 + kblk) ----
__global__ void pack_x_kernel(const float* __restrict__ x,
                              unsigned short* __restrict__ pX) {
    int g    = blockIdx.x * 256 + threadIdx.x;   // 4,194,304 threads
    int lane = g & 63;
    int frag = g >> 6;
    int kblk = frag & 31;
    int mblk = (frag >> 5) & 7;
    int t    = frag >> 8;
    int m = mblk * 16 + (lane & 15);
    int k = kblk * 32 + ((lane >> 4) << 3);
    *reinterpret_cast<uint4*>(pX + (size_t)frag * 512 + lane * 8) =
        pack8(x + (size_t)(t * 128 + m) * 1024 + k);
}

// ---- main persistent LSTM kernel ----
__global__ __launch_bounds__(256, 1) void lstm_main(
    const float* __restrict__ x, const float* __restrict__ h0,
    const float* __restrict__ c0, const float* __restrict__ bias,
    const unsigned short* __restrict__ pB,
    unsigned short* pH, int use_ph,
    const unsigned short* __restrict__ pX, int use_px,
    float* out, int* cnt) {

    __shared__ __align__(16) unsigned short AbufX[2][32][512];  // 64 KiB x A-frags
    __shared__ __align__(16) unsigned short AbufH[2][32][512];  // 64 KiB h A-frags
    __shared__ float g_lds[4][32][17];                          // activated gates
    __shared__ float c_lds[32][16];                             // fp32 cell state
    __shared__ __align__(16) unsigned short hbf_lds[32][16];    // bf16 h staging
    __shared__ int amp_lds[3];                                  // xcd, rank, l2mode

    const int tid  = threadIdx.x;
    const int lane = tid & 63;
    const int w    = tid >> 6;                 // wave index == gate (i,f,g,o)
    const int wg   = blockIdx.x;
    const int r    = (wg >> 3) & 3;            // row group (32 batch rows)
    const int j    = (wg & 7) * 8 + (wg >> 5); // h-col block (16 cols)
    const int col  = lane & 15;
    const int quad = lane >> 4;
    const int nblk = w * 64 + j;

    int* subp = cnt + (r * 8 + (j >> 3)) * 64;  // arrival sub-counter (256B spread)

    const float breg = bias[w * 1024 + j * 16 + col];

    { // init cell state (each thread owns its 2 cells; no cross-thread use)
        float cv = c0[j * 16 + (tid & 15)];
        int row = tid >> 4;
        c_lds[row][tid & 15]      = cv;
        c_lds[row + 16][tid & 15] = cv;
    }

    // ---- XCD identity + leader election + probe publish (part 1) ----
    // cnt ints: [0,2048) sub-counters | 2048+xcd*64 flags (<2496) |
    //   3072+xcd ranks (<3080) | 3200+xcd*64 probes (<3648) | 3840 init bar.
    if (use_ph && tid == 0) {
        int xcc;
        asm volatile("s_getreg_b32 %0, hwreg(20, 0, 32)" : "=s"(xcc));  // XCC_ID
        xcc &= 7;
        int rk = __hip_atomic_fetch_add(cnt + 3072 + xcc, 1, __ATOMIC_RELAXED,
                                        __HIP_MEMORY_SCOPE_AGENT);
        amp_lds[0] = xcc;
        amp_lds[1] = rk;
        if (rk == 0) {  // leader: plain store -> dirty in LOCAL L2 only
            *(volatile int*)(cnt + 3200 + xcc * 64) = 0x5EED0 + xcc;
            asm volatile("s_waitcnt vmcnt(0)" ::: "memory");
        }
        // RELAXED arrive (no wbl2: the probe's L2-locality IS the test)
        __hip_atomic_fetch_add(cnt + 3840, 1, __ATOMIC_RELAXED,
                               __HIP_MEMORY_SCOPE_AGENT);
    }

    // ---- resident weights (overlaps the init-barrier wait below) ----
    const unsigned short* pBw = pB + (size_t)nblk * 64 * 512 + lane * 8;
    short8 bw[64];
#pragma unroll
    for (int kb = 0; kb < 64; ++kb)
        bw[kb] = *reinterpret_cast<const short8*>(pBw + (size_t)kb * 512);

    // ---- init barrier + mapping validation (part 2) ----
    if (use_ph && tid == 0) {
        while (__hip_atomic_load(cnt + 3840, __ATOMIC_RELAXED,
                                 __HIP_MEMORY_SCOPE_AGENT) < 256)
            __builtin_amdgcn_s_sleep(1);
        int probe, xcc = amp_lds[0];
        asm volatile("global_load_dword %0, %1, off sc0\n"
                     "s_waitcnt vmcnt(0)"
                     : "=v"(probe) : "v"(cnt + 3200 + xcc * 64) : "memory");
        // same physical L2 as leader <=> probe hits leader's dirty line
        amp_lds[2] = (probe == 0x5EED0 + xcc) ? 1 : 0;
    } else if (tid == 0) {
        amp_lds[0] = 0; amp_lds[1] = 1; amp_lds[2] = 0;
    }
    __syncthreads();
    const int  xcd     = amp_lds[0];
    const bool is_lead = (use_ph != 0) && (amp_lds[1] == 0);

    // ---- helpers -----------------------------------------------------------
    auto stage_x_full = [&](int tt) {
#pragma unroll
        for (int i = 0; i < 16; ++i) {
            int s = tid + 256 * i;                 // slot in [0,4096)
            int ln = s & 63, kbg = (s >> 6) & 31, mb = s >> 11;
            if (use_px) {
                const unsigned short* src =
                    pX + (((size_t)(tt * 8 + 2 * r + mb) * 32 + kbg) * 512) + ln * 8;
                *reinterpret_cast<uint4*>(&AbufX[mb][kbg][ln * 8]) =
                    *reinterpret_cast<const uint4*>(src);
            } else {
                int m = 32 * r + mb * 16 + (ln & 15);
                int k = kbg * 32 + ((ln >> 4) << 3);
                *reinterpret_cast<uint4*>(&AbufX[mb][kbg][ln * 8]) =
                    pack8(x + (size_t)(tt * 128 + m) * 1024 + k);
            }
        }
    };

    auto stage_h0 = [&]() {    // broadcast h0 over batch rows (t=0 only)
#pragma unroll
        for (int i = 0; i < 16; ++i) {
            int s = tid + 256 * i;
            int ln = s & 63, kbg = (s >> 6) & 31, mb = s >> 11;
            int k = kbg * 32 + ((ln >> 4) << 3);
            union { uint4 v; unsigned short u[8]; } tv;
#pragma unroll
            for (int jj = 0; jj < 8; ++jj) tv.u[jj] = f2bf(h0[k + jj]);
            *reinterpret_cast<uint4*>(&AbufH[mb][kbg][ln * 8]) = tv.v;
        }
    };

    auto stage_h_out = [&](int tt) {   // !use_ph fallback: h from out via L2
#pragma unroll
        for (int i = 0; i < 16; ++i) {
            int s = tid + 256 * i;
            int ln = s & 63, kbg = (s >> 6) & 31, mb = s >> 11;
            int m = 32 * r + mb * 16 + (ln & 15);
            int k = kbg * 32 + ((ln >> 4) << 3);
            *reinterpret_cast<uint4*>(&AbufH[mb][kbg][ln * 8]) =
                pack8(out + (size_t)(tt - 1) * 131072 + (size_t)m * 1024 + k);
        }
    };

    auto gemm_x = [&](floatx4& A0, floatx4& A1) {   // B-frags bw[0..31]
#pragma unroll
        for (int kb = 0; kb < 32; ++kb) {
            short8 a0 = *reinterpret_cast<const short8*>(&AbufX[0][kb][lane * 8]);
            short8 a1 = *reinterpret_cast<const short8*>(&AbufX[1][kb][lane * 8]);
            A0 = __builtin_amdgcn_mfma_f32_16x16x32_bf16(a0, bw[kb], A0, 0, 0, 0);
            A1 = __builtin_amdgcn_mfma_f32_16x16x32_bf16(a1, bw[kb], A1, 0, 0, 0);
        }
    };
    auto gemm_h = [&](floatx4& A0, floatx4& A1) {   // B-frags bw[32..63]
#pragma unroll
        for (int kb = 0; kb < 32; ++kb) {
            short8 a0 = *reinterpret_cast<const short8*>(&AbufH[0][kb][lane * 8]);
            short8 a1 = *reinterpret_cast<const short8*>(&AbufH[1][kb][lane * 8]);
            A0 = __builtin_amdgcn_mfma_f32_16x16x32_bf16(a0, bw[32 + kb], A0, 0, 0, 0);
            A1 = __builtin_amdgcn_mfma_f32_16x16x32_bf16(a1, bw[32 + kb], A1, 0, 0, 0);
        }
    };
    // ------------------------------------------------------------------------

    // prologue: stage x(0)
    stage_x_full(0);
    asm volatile("s_waitcnt lgkmcnt(0)" ::: "memory");
    __builtin_amdgcn_s_barrier();          // AbufX(0) ready

    for (int t = 0; t < 256; ++t) {
        const int parity = t & 1;

        // ---- 1. global poll + leader inv + local flag wait ----
        if (t > 0) {
            if (tid < 8) {
                int* sp = cnt + (r * 8 + tid) * 64;
                const int target = 8 * t;
                while (true) {
                    int vv = __hip_atomic_load(sp, __ATOMIC_RELAXED,
                                               __HIP_MEMORY_SCOPE_AGENT);
                    if (__ballot(vv >= target) == 0xFFull) break;
                    __builtin_amdgcn_s_sleep(1);
                }
                if (!use_ph)   // fallback moves h through L2 -> must invalidate
                    __builtin_amdgcn_fence(__ATOMIC_ACQUIRE, "agent");
            }
            if (tid == 0) {
                if (is_lead) {  // one L2 invalidate per XCD per step + flag
                    __builtin_amdgcn_fence(__ATOMIC_ACQUIRE, "agent");  // inv
                    asm volatile("s_waitcnt vmcnt(0)" ::: "memory");
                    *(volatile int*)(cnt + 2048 + xcd * 64) = t;
                    asm volatile("s_waitcnt vmcnt(0)" ::: "memory");
                }
                if (amp_lds[2]) {  // wait for this XCD's inv; sticky-demote on
                    const int* fp = cnt + 2048 + xcd * 64;   // timeout (safety)
                    int fv, spins = 0;
                    while (true) {
                        asm volatile("global_load_dword %0, %1, off sc0\n"
                                     "s_waitcnt vmcnt(0)"
                                     : "=v"(fv) : "v"(fp) : "memory");
                        if (fv >= t) break;
                        if (++spins > (1 << 15)) { amp_lds[2] = 0; break; }
                        __builtin_amdgcn_s_sleep(1);
                    }
                    asm volatile("s_waitcnt lgkmcnt(0)" ::: "memory");
                }
            }
        }
        __builtin_amdgcn_s_barrier();      // B1: h(t-1) visible to this XCD
        const int l2m = amp_lds[2];        // (re-read: demotion is sticky)

        // ---- 2. issue h(t-1) loads to registers (no wait) ----
        uint4 hreg[16];
        if (t == 0) {
            stage_h0();
        } else if (use_ph) {
            const char* bb2 = (const char*)pH + (size_t)parity * 262144 +
                              (size_t)r * 65536 + (size_t)tid * 16;
            if (l2m) {          // L2-amplified: L1-bypass, L2-cached
#pragma unroll
                for (int i = 0; i < 16; ++i)
                    asm volatile("global_load_dwordx4 %0, %1, off sc0"
                                 : "=v"(hreg[i]) : "v"(bb2 + (size_t)i * 4096) : "memory");
            } else {            // demoted: IF path (R7-identical)
#pragma unroll
                for (int i = 0; i < 16; ++i)
                    asm volatile("global_load_dwordx4 %0, %1, off sc0 sc1"
                                 : "=v"(hreg[i]) : "v"(bb2 + (size_t)i * 4096) : "memory");
            }
        } else {
            stage_h_out(t);
        }

        // ---- 3. x-GEMM runs under the in-flight h loads ----
        floatx4 acc0 = {0.f, 0.f, 0.f, 0.f}, acc1 = {0.f, 0.f, 0.f, 0.f};
        gemm_x(acc0, acc1);

        // ---- 4. drain h loads, write to LDS ----
        if (t > 0 && use_ph) {
            __builtin_amdgcn_sched_barrier(0);
            asm volatile("s_waitcnt vmcnt(0)" ::: "memory");
            __builtin_amdgcn_sched_barrier(0);
            unsigned short* ld = &AbufH[0][0][0] + tid * 8;
#pragma unroll
            for (int i = 0; i < 16; ++i)
                *reinterpret_cast<uint4*>(ld + i * 2048) = hreg[i];
        }
        __syncthreads();   // B2: AbufH ready

        // ---- 5. h-GEMM ----
        gemm_h(acc0, acc1);

        // ---- 6. epilogue: bias + activation into LDS ----
        // D layout (m89): row = quad*4 + rr, col = lane&15
#pragma unroll
        for (int rr = 0; rr < 4; ++rr) {
            float p0 = acc0[rr] + breg;
            float p1 = acc1[rr] + breg;
            float v0, v1;
            if (w == 2) { v0 = tanhf(p0); v1 = tanhf(p1); }
            else        { v0 = 1.f / (1.f + __expf(-p0)); v1 = 1.f / (1.f + __expf(-p1)); }
            g_lds[w][quad * 4 + rr][col]      = v0;
            g_lds[w][16 + quad * 4 + rr][col] = v1;
        }
        __syncthreads();   // B3: gates ready; AbufH reads done

        // ---- 7. cell update (fp32); hv/c kept in registers ----
        const int row0 = tid >> 4, cc = tid & 15;
        float hv0, hv1, cn0, cn1;
        {
            float iv = g_lds[0][row0][cc];
            float fv = g_lds[1][row0][cc];
            float gv = g_lds[2][row0][cc];
            float ov = g_lds[3][row0][cc];
            cn0 = fv * c_lds[row0][cc] + iv * gv;
            hv0 = ov * tanhf(cn0);
            c_lds[row0][cc]   = cn0;
            hbf_lds[row0][cc] = f2bf(hv0);
            int row1 = row0 + 16;
            iv = g_lds[0][row1][cc];
            fv = g_lds[1][row1][cc];
            gv = g_lds[2][row1][cc];
            ov = g_lds[3][row1][cc];
            cn1 = fv * c_lds[row1][cc] + iv * gv;
            hv1 = ov * tanhf(cn1);
            c_lds[row1][cc]   = cn1;
            hbf_lds[row1][cc] = f2bf(hv1);
        }
        __syncthreads();   // B4: hbf_lds ready for publish

        auto store_out = [&]() {
            const long hidbase = (long)t * 131072;
            const long m0 = 32 * r + row0, m1 = m0 + 16;
            out[hidbase + m0 * 1024 + j * 16 + cc] = hv0;
            out[hidbase + m1 * 1024 + j * 16 + cc] = hv1;
            if (t == 255) {
                out[HID_OFF + m0 * 1024 + j * 16 + cc] = hv0;
                out[HID_OFF + m1 * 1024 + j * 16 + cc] = hv1;
                out[CT_OFF  + m0 * 1024 + j * 16 + cc] = cn0;
                out[CT_OFF  + m1 * 1024 + j * 16 + cc] = cn1;
            }
        };

        if (!use_ph) store_out();   // fallback: out IS the exchange medium

        if (t < 255) {
            // ---- 8. publish h(t): coherent (IF) bf16 stores, wave 0 ----
            if (use_ph && tid < 64) {
                int ml = tid >> 1, cg = tid & 1;
                int m = 32 * r + ml, kcol = j * 16 + cg * 8;
                int frag  = (2 * r + (ml >> 4)) * 32 + (kcol >> 5);
                int lanep = (m & 15) + 16 * ((kcol & 31) >> 3);
                unsigned short* dst = pH + (size_t)(parity ^ 1) * 131072 +
                                      (size_t)frag * 512 + lanep * 8;
                const unsigned long long* sv =
                    reinterpret_cast<const unsigned long long*>(&hbf_lds[ml][cg * 8]);
                unsigned long long* d64 = reinterpret_cast<unsigned long long*>(dst);
                __hip_atomic_store(d64, sv[0], __ATOMIC_RELAXED,
                                   __HIP_MEMORY_SCOPE_AGENT);
                __hip_atomic_store(d64 + 1, sv[1], __ATOMIC_RELAXED,
                                   __HIP_MEMORY_SCOPE_AGENT);
            }
            // ---- 9. arrive ----
            if (tid == 0) {
                if (use_ph) {
                    asm volatile("s_waitcnt vmcnt(0)" ::: "memory");
                    __hip_atomic_fetch_add(subp, 1, __ATOMIC_RELAXED,
                                           __HIP_MEMORY_SCOPE_AGENT);
                } else {
                    __hip_atomic_fetch_add(subp, 1, __ATOMIC_RELEASE,
                                           __HIP_MEMORY_SCOPE_AGENT);
                }
            }
        }

        if (use_ph) store_out();    // off the critical path

        // ---- 10. x prefetch for t+1 (overlaps straggler window) ----
        if (t < 255) stage_x_full(t + 1);
        asm volatile("s_waitcnt lgkmcnt(0)" ::: "memory");
        __builtin_amdgcn_s_barrier();   // tail: AbufX(t+1) ready; no vmcnt drain
    }
}

extern "C" void kernel_launch(void* const* d_in, const int* in_sizes, int n_in,
                              void* d_out, int out_size, void* d_ws, size_t ws_size,
                              hipStream_t stream) {
    (void)in_sizes; (void)n_in; (void)out_size;
    const float* x    = (const float*)d_in[0];
    const float* h0   = (const float*)d_in[1];
    const float* c0   = (const float*)d_in[2];
    const float* wih  = (const float*)d_in[3];
    const float* whh  = (const float*)d_in[4];
    const float* bias = (const float*)d_in[5];
    float* out = (float*)d_out;

    char* ws = (char*)d_ws;
    int* counters = (int*)ws;                 // 16 KiB: sub-counters|flags|ranks|probes
    const size_t SZB = 2048ull * 4096 * 2;    // 16 MiB packed weights
    const size_t SZH = 2ull * 256 * 512 * 2;  // 512 KiB packed-h ping-pong
    const size_t SZX = 65536ull * 512 * 2;    // 64 MiB packed x

    size_t off = 16384;
    unsigned short* pB;
    if (ws_size >= off + SZB) {               // weights in ws
        pB = (unsigned short*)(ws + off); off += SZB;
    } else {                                  // tier D: weights in out tail
        // Safe with register-resident weights: loaded before step 0; out rows
        // [224,256) first written at t=224 (needs 224 sync rounds).
        pB = (unsigned short*)(out + WTAIL_F);
    }
    int use_ph = (ws_size >= off + SZH) ? 1 : 0;
    unsigned short* pH = use_ph ? (unsigned short*)(ws + off) : (unsigned short*)0;
    if (use_ph) off += SZH;
    int use_px = (ws_size >= off + SZX) ? 1 : 0;
    unsigned short* pX = use_px ? (unsigned short*)(ws + off) : (unsigned short*)0;

    hipMemsetAsync(ws, 0, 16384, stream);                     // counters+flags+probes
    pack_w_kernel<<<4096, 256, 0, stream>>>(wih, whh, pB);
    if (use_px) pack_x_kernel<<<16384, 256, 0, stream>>>(x, pX);

    lstm_main<<<dim3(256), dim3(256), 0, stream>>>(
        x, h0, c0, bias, pB, pH, use_ph, pX, use_px, out, counters);
}

// Round 8
// 3256.023 us; speedup vs baseline: 3.8246x; 3.8246x over previous
//
#include <hip/hip_runtime.h>
#include <hip/hip_bf16.h>

// ---------------------------------------------------------------------------
// LSTM: T=256, B=128, F=1024, H=1024.  gates = [x_t | h] @ [W_ih; W_hh] + bias
// Persistent kernel, 256 WGs. r=(wg>>3)&3 (32-row group), j=(wg&7)*8+(wg>>5)
// (16-col group). Wave = gate. bf16 MFMA 16x16x32. All 64 B-fragments
// register-resident (R4). Direct gather-poll (R6). Batched asm h-loads +
// gemm_x overlap (R7).
//
// R11: FRESH-ADDRESS h EXCHANGE (L2 amplification WITHOUT invalidates).
// Evidence: h-read is byte-bound on the coherent path (16 MiB/step; R5 vs
// R7 equal at 2x request count; latency cuts null). R10 proved per-step
// L2-invalidate protocols are poisonous (-3.9x). Fix: publish h(t) into a
// NEVER-REUSED 256 KiB slot (64 MiB ring, slot=t). Readers use PLAIN cached
// loads: an L2 can't hold a stale copy of a line it has never seen, so no
// fence/inv is needed. First toucher per XCD misses to MALL (publish was
// sc0sc1 write-through; MALL is memory-side so the miss path sees it);
// the other ~31 WGs hit local L2 => MALL reads drop 16 -> ~2 MiB/step.
// Ordering = proven R5/R7 chain (publish -> vmcnt(0) -> arrive; poll ->
// load). pX is dropped if the 64 MiB ring displaces it (x then staged from
// raw fp32 via pack8 at the step tail, off the critical path).
// Fallback tiers: use_pht -> use_ph (R7 sc0sc1 ping-pong) -> out-medium.
// Workspace: counters(16K) | pB(16M) | pHt(63.75M) | [pH 512K] | [pX 64M];
// tier D: pB packed into out rows [224,256).
// ---------------------------------------------------------------------------

typedef __attribute__((ext_vector_type(8))) short short8;   // 8 bf16 = 4 VGPRs
typedef __attribute__((ext_vector_type(4))) float floatx4;  // MFMA accumulator

#define HID_OFF 33554432L   // T*B*H
#define CT_OFF  33685504L   // T*B*H + B*H
#define WTAIL_F 29360128L   // 224*131072 : float offset of hid rows [224,256)

__device__ __forceinline__ unsigned short f2bf(float f) {
    __hip_bfloat16 hb = __float2bfloat16(f);
    return *reinterpret_cast<unsigned short*>(&hb);
}

// 8 contiguous fp32 -> 8 bf16 packed in a uint4
__device__ __forceinline__ uint4 pack8(const float* p) {
    float4 f0 = *reinterpret_cast<const float4*>(p);
    float4 f1 = *reinterpret_cast<const float4*>(p + 4);
    union { uint4 v; unsigned short u[8]; } t;
    t.u[0] = f2bf(f0.x); t.u[1] = f2bf(f0.y); t.u[2] = f2bf(f0.z); t.u[3] = f2bf(f0.w);
    t.u[4] = f2bf(f1.x); t.u[5] = f2bf(f1.y); t.u[6] = f2bf(f1.z); t.u[7] = f2bf(f1.w);
    return t.v;
}

// ---- pack weights into B-fragment order: frag=(nblk*64+kblk), lane, 8 bf16 ----
__global__ void pack_w_kernel(const float* __restrict__ wih,
                              const float* __restrict__ whh,
                              unsigned short* __restrict__ pB) {
    int g    = blockIdx.x * 256 + threadIdx.x;   // 1,048,576 threads
    int lane = g & 63;
    int frag = g >> 6;
    int kblk = frag & 63;
    int nblk = frag >> 6;
    int n = nblk * 16 + (lane & 15);
    int k = kblk * 32 + ((lane >> 4) << 3);
    const float* src = (k < 1024) ? (wih + (size_t)k * 4096 + n)
                                  : (whh + (size_t)(k - 1024) * 4096 + n);
    __attribute__((aligned(16))) unsigned short tmp[8];
#pragma unroll
    for (int jj = 0; jj < 8; ++jj) tmp[jj] = f2bf(src[(size_t)jj * 4096]);
    *reinterpret_cast<uint4*>(pB + (size_t)frag * 512 + lane * 8) =
        *reinterpret_cast<const uint4*>(tmp);
}

// ---- pack x into A-fragment order: frag=(t*256 + mblk*32 + kblk) ----
__global__ void pack_x_kernel(const float* __restrict__ x,
                              unsigned short* __restrict__ pX) {
    int g    = blockIdx.x * 256 + threadIdx.x;   // 4,194,304 threads
    int lane = g & 63;
    int frag = g >> 6;
    int kblk = frag & 31;
    int mblk = (frag >> 5) & 7;
    int t    = frag >> 8;
    int m = mblk * 16 + (lane & 15);
    int k = kblk * 32 + ((lane >> 4) << 3);
    *reinterpret_cast<uint4*>(pX + (size_t)frag * 512 + lane * 8) =
        pack8(x + (size_t)(t * 128 + m) * 1024 + k);
}

// ---- main persistent LSTM kernel ----
__global__ __launch_bounds__(256, 1) void lstm_main(
    const float* __restrict__ x, const float* __restrict__ h0,
    const float* __restrict__ c0, const float* __restrict__ bias,
    const unsigned short* __restrict__ pB,
    unsigned short* pHt, int use_pht,
    unsigned short* pH, int use_ph,
    const unsigned short* __restrict__ pX, int use_px,
    float* out, int* cnt) {

    __shared__ __align__(16) unsigned short AbufX[2][32][512];  // 64 KiB x A-frags
    __shared__ __align__(16) unsigned short AbufH[2][32][512];  // 64 KiB h A-frags
    __shared__ float g_lds[4][32][17];                          // activated gates
    __shared__ float c_lds[32][16];                             // fp32 cell state
    __shared__ __align__(16) unsigned short hbf_lds[32][16];    // bf16 h staging

    const int tid  = threadIdx.x;
    const int lane = tid & 63;
    const int w    = tid >> 6;                 // wave index == gate (i,f,g,o)
    const int wg   = blockIdx.x;
    const int r    = (wg >> 3) & 3;            // row group (32 batch rows)
    const int j    = (wg & 7) * 8 + (wg >> 5); // h-col block (16 cols)
    const int col  = lane & 15;
    const int quad = lane >> 4;
    const int nblk = w * 64 + j;

    const int use_hx = use_pht | use_ph;        // any packed-h exchange medium

    int* subp = cnt + (r * 8 + (j >> 3)) * 64;  // arrival sub-counter (256B spread)

    const float breg = bias[w * 1024 + j * 16 + col];

    { // init cell state (each thread owns its 2 cells; no cross-thread use)
        float cv = c0[j * 16 + (tid & 15)];
        int row = tid >> 4;
        c_lds[row][tid & 15]      = cv;
        c_lds[row + 16][tid & 15] = cv;
    }

    // ---- resident weights: all 64 B-fragments (x-half kb 0..31, h 32..63) ----
    const unsigned short* pBw = pB + (size_t)nblk * 64 * 512 + lane * 8;
    short8 bw[64];
#pragma unroll
    for (int kb = 0; kb < 64; ++kb)
        bw[kb] = *reinterpret_cast<const short8*>(pBw + (size_t)kb * 512);

    // ---- helpers -----------------------------------------------------------
    auto stage_x_full = [&](int tt) {
#pragma unroll
        for (int i = 0; i < 16; ++i) {
            int s = tid + 256 * i;                 // slot in [0,4096)
            int ln = s & 63, kbg = (s >> 6) & 31, mb = s >> 11;
            if (use_px) {
                const unsigned short* src =
                    pX + (((size_t)(tt * 8 + 2 * r + mb) * 32 + kbg) * 512) + ln * 8;
                *reinterpret_cast<uint4*>(&AbufX[mb][kbg][ln * 8]) =
                    *reinterpret_cast<const uint4*>(src);
            } else {
                int m = 32 * r + mb * 16 + (ln & 15);
                int k = kbg * 32 + ((ln >> 4) << 3);
                *reinterpret_cast<uint4*>(&AbufX[mb][kbg][ln * 8]) =
                    pack8(x + (size_t)(tt * 128 + m) * 1024 + k);
            }
        }
    };

    auto stage_h0 = [&]() {    // broadcast h0 over batch rows (t=0 only)
#pragma unroll
        for (int i = 0; i < 16; ++i) {
            int s = tid + 256 * i;
            int ln = s & 63, kbg = (s >> 6) & 31, mb = s >> 11;
            int k = kbg * 32 + ((ln >> 4) << 3);
            union { uint4 v; unsigned short u[8]; } tv;
#pragma unroll
            for (int jj = 0; jj < 8; ++jj) tv.u[jj] = f2bf(h0[k + jj]);
            *reinterpret_cast<uint4*>(&AbufH[mb][kbg][ln * 8]) = tv.v;
        }
    };

    auto stage_h_out = [&](int tt) {   // !use_hx fallback: h from out via L2
#pragma unroll
        for (int i = 0; i < 16; ++i) {
            int s = tid + 256 * i;
            int ln = s & 63, kbg = (s >> 6) & 31, mb = s >> 11;
            int m = 32 * r + mb * 16 + (ln & 15);
            int k = kbg * 32 + ((ln >> 4) << 3);
            *reinterpret_cast<uint4*>(&AbufH[mb][kbg][ln * 8]) =
                pack8(out + (size_t)(tt - 1) * 131072 + (size_t)m * 1024 + k);
        }
    };

    auto gemm_x = [&](floatx4& A0, floatx4& A1) {   // B-frags bw[0..31]
#pragma unroll
        for (int kb = 0; kb < 32; ++kb) {
            short8 a0 = *reinterpret_cast<const short8*>(&AbufX[0][kb][lane * 8]);
            short8 a1 = *reinterpret_cast<const short8*>(&AbufX[1][kb][lane * 8]);
            A0 = __builtin_amdgcn_mfma_f32_16x16x32_bf16(a0, bw[kb], A0, 0, 0, 0);
            A1 = __builtin_amdgcn_mfma_f32_16x16x32_bf16(a1, bw[kb], A1, 0, 0, 0);
        }
    };
    auto gemm_h = [&](floatx4& A0, floatx4& A1) {   // B-frags bw[32..63]
#pragma unroll
        for (int kb = 0; kb < 32; ++kb) {
            short8 a0 = *reinterpret_cast<const short8*>(&AbufH[0][kb][lane * 8]);
            short8 a1 = *reinterpret_cast<const short8*>(&AbufH[1][kb][lane * 8]);
            A0 = __builtin_amdgcn_mfma_f32_16x16x32_bf16(a0, bw[32 + kb], A0, 0, 0, 0);
            A1 = __builtin_amdgcn_mfma_f32_16x16x32_bf16(a1, bw[32 + kb], A1, 0, 0, 0);
        }
    };
    // ------------------------------------------------------------------------

    // prologue: stage x(0)
    __syncthreads();
    stage_x_full(0);
    asm volatile("s_waitcnt lgkmcnt(0)" ::: "memory");
    __builtin_amdgcn_s_barrier();          // AbufX(0) ready

    for (int t = 0; t < 256; ++t) {
        const int parity = t & 1;

        // ---- 1. global poll: all 8 sub-counters of this row group ----
        if (t > 0 && tid < 8) {
            int* sp = cnt + (r * 8 + tid) * 64;
            const int target = 8 * t;
            while (true) {
                int vv = __hip_atomic_load(sp, __ATOMIC_RELAXED,
                                           __HIP_MEMORY_SCOPE_AGENT);
                if (__ballot(vv >= target) == 0xFFull) break;
                __builtin_amdgcn_s_sleep(1);
            }
            if (!use_hx)   // out-medium fallback: must invalidate L2
                __builtin_amdgcn_fence(__ATOMIC_ACQUIRE, "agent");
        }
        __builtin_amdgcn_s_barrier();      // B1: release seen by all waves

        // ---- 2. issue h(t-1) loads to registers (no wait) ----
        uint4 hreg[16];
        if (t == 0) {
            stage_h0();
        } else if (use_pht) {
            // fresh slot (t-1): plain cached loads. The local L2 has never
            // seen these lines => cannot be stale; first toucher fetches
            // from MALL (publish was write-through), rest hit local L2.
            const char* bb2 = (const char*)pHt + (size_t)(t - 1) * 262144 +
                              (size_t)r * 65536 + (size_t)tid * 16;
#pragma unroll
            for (int i = 0; i < 16; ++i)
                asm volatile("global_load_dwordx4 %0, %1, off"
                             : "=v"(hreg[i]) : "v"(bb2 + (size_t)i * 4096) : "memory");
        } else if (use_ph) {
            // R7 fallback: ping-pong + coherent (IF) reads
            const char* bb2 = (const char*)pH + (size_t)parity * 262144 +
                              (size_t)r * 65536 + (size_t)tid * 16;
#pragma unroll
            for (int i = 0; i < 16; ++i)
                asm volatile("global_load_dwordx4 %0, %1, off sc0 sc1"
                             : "=v"(hreg[i]) : "v"(bb2 + (size_t)i * 4096) : "memory");
        } else {
            stage_h_out(t);
        }

        // ---- 3. x-GEMM runs under the in-flight h loads ----
        floatx4 acc0 = {0.f, 0.f, 0.f, 0.f}, acc1 = {0.f, 0.f, 0.f, 0.f};
        gemm_x(acc0, acc1);

        // ---- 4. drain h loads, write to LDS ----
        if (t > 0 && use_hx) {
            __builtin_amdgcn_sched_barrier(0);
            asm volatile("s_waitcnt vmcnt(0)" ::: "memory");
            __builtin_amdgcn_sched_barrier(0);
            unsigned short* ld = &AbufH[0][0][0] + tid * 8;
#pragma unroll
            for (int i = 0; i < 16; ++i)
                *reinterpret_cast<uint4*>(ld + i * 2048) = hreg[i];
        }
        __syncthreads();   // B2: AbufH ready

        // ---- 5. h-GEMM ----
        gemm_h(acc0, acc1);

        // ---- 6. epilogue: bias + activation into LDS ----
        // D layout (m89): row = quad*4 + rr, col = lane&15
#pragma unroll
        for (int rr = 0; rr < 4; ++rr) {
            float p0 = acc0[rr] + breg;
            float p1 = acc1[rr] + breg;
            float v0, v1;
            if (w == 2) { v0 = tanhf(p0); v1 = tanhf(p1); }
            else        { v0 = 1.f / (1.f + __expf(-p0)); v1 = 1.f / (1.f + __expf(-p1)); }
            g_lds[w][quad * 4 + rr][col]      = v0;
            g_lds[w][16 + quad * 4 + rr][col] = v1;
        }
        __syncthreads();   // B3: gates ready; AbufH reads done

        // ---- 7. cell update (fp32); hv/c kept in registers ----
        const int row0 = tid >> 4, cc = tid & 15;
        float hv0, hv1, cn0, cn1;
        {
            float iv = g_lds[0][row0][cc];
            float fv = g_lds[1][row0][cc];
            float gv = g_lds[2][row0][cc];
            float ov = g_lds[3][row0][cc];
            cn0 = fv * c_lds[row0][cc] + iv * gv;
            hv0 = ov * tanhf(cn0);
            c_lds[row0][cc]   = cn0;
            hbf_lds[row0][cc] = f2bf(hv0);
            int row1 = row0 + 16;
            iv = g_lds[0][row1][cc];
            fv = g_lds[1][row1][cc];
            gv = g_lds[2][row1][cc];
            ov = g_lds[3][row1][cc];
            cn1 = fv * c_lds[row1][cc] + iv * gv;
            hv1 = ov * tanhf(cn1);
            c_lds[row1][cc]   = cn1;
            hbf_lds[row1][cc] = f2bf(hv1);
        }
        __syncthreads();   // B4: hbf_lds ready for publish

        auto store_out = [&]() {
            const long hidbase = (long)t * 131072;
            const long m0 = 32 * r + row0, m1 = m0 + 16;
            out[hidbase + m0 * 1024 + j * 16 + cc] = hv0;
            out[hidbase + m1 * 1024 + j * 16 + cc] = hv1;
            if (t == 255) {
                out[HID_OFF + m0 * 1024 + j * 16 + cc] = hv0;
                out[HID_OFF + m1 * 1024 + j * 16 + cc] = hv1;
                out[CT_OFF  + m0 * 1024 + j * 16 + cc] = cn0;
                out[CT_OFF  + m1 * 1024 + j * 16 + cc] = cn1;
            }
        };

        if (!use_hx) store_out();   // fallback: out IS the exchange medium

        if (t < 255) {
            // ---- 8. publish h(t): write-through bf16 stores, wave 0 ----
            if (use_hx && tid < 64) {
                int ml = tid >> 1, cg = tid & 1;
                int m = 32 * r + ml, kcol = j * 16 + cg * 8;
                int frag  = (2 * r + (ml >> 4)) * 32 + (kcol >> 5);
                int lanep = (m & 15) + 16 * ((kcol & 31) >> 3);
                unsigned short* dst = use_pht
                    ? pHt + (size_t)t * 131072 + (size_t)frag * 512 + lanep * 8
                    : pH + (size_t)(parity ^ 1) * 131072 + (size_t)frag * 512 + lanep * 8;
                const unsigned long long* sv =
                    reinterpret_cast<const unsigned long long*>(&hbf_lds[ml][cg * 8]);
                unsigned long long* d64 = reinterpret_cast<unsigned long long*>(dst);
                __hip_atomic_store(d64, sv[0], __ATOMIC_RELAXED,
                                   __HIP_MEMORY_SCOPE_AGENT);
                __hip_atomic_store(d64 + 1, sv[1], __ATOMIC_RELAXED,
                                   __HIP_MEMORY_SCOPE_AGENT);
            }
            // ---- 9. arrive ----
            if (tid == 0) {
                if (use_hx) {
                    asm volatile("s_waitcnt vmcnt(0)" ::: "memory");
                    __hip_atomic_fetch_add(subp, 1, __ATOMIC_RELAXED,
                                           __HIP_MEMORY_SCOPE_AGENT);
                } else {
                    __hip_atomic_fetch_add(subp, 1, __ATOMIC_RELEASE,
                                           __HIP_MEMORY_SCOPE_AGENT);
                }
            }
        }

        if (use_hx) store_out();    // off the critical path

        // ---- 10. x prefetch for t+1 (overlaps straggler window) ----
        if (t < 255) stage_x_full(t + 1);
        asm volatile("s_waitcnt lgkmcnt(0)" ::: "memory");
        __builtin_amdgcn_s_barrier();   // tail: AbufX(t+1) ready; no vmcnt drain
    }
}

extern "C" void kernel_launch(void* const* d_in, const int* in_sizes, int n_in,
                              void* d_out, int out_size, void* d_ws, size_t ws_size,
                              hipStream_t stream) {
    (void)in_sizes; (void)n_in; (void)out_size;
    const float* x    = (const float*)d_in[0];
    const float* h0   = (const float*)d_in[1];
    const float* c0   = (const float*)d_in[2];
    const float* wih  = (const float*)d_in[3];
    const float* whh  = (const float*)d_in[4];
    const float* bias = (const float*)d_in[5];
    float* out = (float*)d_out;

    char* ws = (char*)d_ws;
    int* counters = (int*)ws;                 // 16 KiB counter region (spread lines)
    const size_t SZB  = 2048ull * 4096 * 2;   // 16 MiB packed weights
    const size_t SZHT = 255ull * 262144;      // 63.75 MiB fresh-slot h ring
    const size_t SZH  = 2ull * 256 * 512 * 2; // 512 KiB packed-h ping-pong
    const size_t SZX  = 65536ull * 512 * 2;   // 64 MiB packed x

    size_t off = 16384;
    unsigned short* pB;
    if (ws_size >= off + SZB) {               // weights in ws
        pB = (unsigned short*)(ws + off); off += SZB;
    } else {                                  // tier D: weights in out tail
        // Safe with register-resident weights: loaded before step 0; out rows
        // [224,256) first written at t=224 (needs 224 sync rounds).
        pB = (unsigned short*)(out + WTAIL_F);
    }
    int use_pht = 0; unsigned short* pHt = 0;
    if (ws_size >= off + SZHT) {              // fresh-slot ring (priority)
        pHt = (unsigned short*)(ws + off); off += SZHT; use_pht = 1;
    }
    int use_ph = 0; unsigned short* pH = 0;
    if (!use_pht && ws_size >= off + SZH) {   // R7 ping-pong fallback
        pH = (unsigned short*)(ws + off); off += SZH; use_ph = 1;
    }
    int use_px = (ws_size >= off + SZX) ? 1 : 0;
    unsigned short* pX = use_px ? (unsigned short*)(ws + off) : (unsigned short*)0;

    hipMemsetAsync(ws, 0, 16384, stream);                     // barrier counters
    pack_w_kernel<<<4096, 256, 0, stream>>>(wih, whh, pB);
    if (use_px) pack_x_kernel<<<16384, 256, 0, stream>>>(x, pX);

    lstm_main<<<dim3(256), dim3(256), 0, stream>>>(
        x, h0, c0, bias, pB, pHt, use_pht, pH, use_ph, pX, use_px, out, counters);
}